// Round 5
// baseline (853.832 us; speedup 1.0000x reference)
//
#include <hip/hip_runtime.h>
#include <hip/hip_bf16.h>

#define EMB 1024
#define HEADS 16
#define HDIM 64
#define FFDIM 4096
#define BSZ 4
#define SEQ 2048
#define MROWS (BSZ * SEQ)

typedef __attribute__((ext_vector_type(8))) short bf16x8;
typedef __attribute__((ext_vector_type(4))) float f32x4;
typedef __attribute__((ext_vector_type(4))) unsigned short u16x4;
typedef unsigned short u16;

__device__ __forceinline__ float bf2f(u16 u) {
  union { unsigned int i; float f; } c; c.i = ((unsigned int)u) << 16; return c.f;
}
__device__ __forceinline__ u16 f2bf(float f) {
  union { float f; unsigned int i; } c; c.f = f;
  unsigned int i = c.i + 0x7fff + ((c.i >> 16) & 1);
  return (u16)(i >> 16);
}
__device__ __forceinline__ void gload16(const u16* g, void* lds) {
  __builtin_amdgcn_global_load_lds(
      (const __attribute__((address_space(1))) void*)g,
      (__attribute__((address_space(3))) void*)lds, 16, 0, 0);
}

// ---- LayerNorm: f32 in -> bf16 out, one wave per row (4 rows/block) ------
__global__ __launch_bounds__(256) void ln_kernel(
    const float* __restrict__ x, const float* __restrict__ g,
    const float* __restrict__ be, u16* __restrict__ out) {
  int w = threadIdx.x >> 6, l = threadIdx.x & 63;
  size_t row = (size_t)blockIdx.x * 4 + w;
  const float* xr = x + row * EMB;
  float f[4][4];
  float s = 0.f, s2 = 0.f;
#pragma unroll
  for (int c = 0; c < 4; ++c) {
    f32x4 v = *(const f32x4*)(xr + c * 256 + l * 4);
#pragma unroll
    for (int j = 0; j < 4; ++j) {
      f[c][j] = v[j];
      s += v[j];
      s2 += v[j] * v[j];
    }
  }
#pragma unroll
  for (int m = 1; m < 64; m <<= 1) {
    s  += __shfl_xor(s, m);
    s2 += __shfl_xor(s2, m);
  }
  float mu = s * (1.f / EMB);
  float var = s2 * (1.f / EMB) - mu * mu;
  float rs = rsqrtf(var + 1e-5f);
#pragma unroll
  for (int c = 0; c < 4; ++c) {
    u16x4 o;
#pragma unroll
    for (int j = 0; j < 4; ++j) {
      int col = c * 256 + l * 4 + j;
      o[j] = f2bf((f[c][j] - mu) * rs * g[col] + be[col]);
    }
    *(u16x4*)(out + row * EMB + c * 256 + l * 4) = o;
  }
}

// ---- convert+transpose: f32 [R][C] -> bf16 [C][R] ------------------------
__global__ __launch_bounds__(256) void transpose_cvt(
    const float* __restrict__ in, u16* __restrict__ out, int R, int C) {
  __shared__ u16 tile[32][33];
  int c0 = blockIdx.x * 32, r0 = blockIdx.y * 32;
  int tx = threadIdx.x, ty = threadIdx.y;
#pragma unroll
  for (int i = ty; i < 32; i += 8)
    tile[i][tx] = f2bf(in[(size_t)(r0 + i) * C + c0 + tx]);
  __syncthreads();
#pragma unroll
  for (int i = ty; i < 32; i += 8)
    out[(size_t)(c0 + i) * R + r0 + tx] = tile[tx][i];
}

// ---- per-head V transpose: bf16 [b][s][h*64+d] -> Vt[bh][d][s] -----------
__global__ __launch_bounds__(256) void transpose_v(
    const u16* __restrict__ V, u16* __restrict__ Vt) {
  __shared__ u16 tile[32][33];
  int s0 = blockIdx.x * 32, d0 = blockIdx.y * 32, bh = blockIdx.z;
  int h = bh % HEADS, b = bh / HEADS;
  int tx = threadIdx.x, ty = threadIdx.y;
  const u16* src = V + (size_t)b * SEQ * EMB + h * HDIM;
  u16* dst = Vt + (size_t)bh * HDIM * SEQ;
#pragma unroll
  for (int i = ty; i < 32; i += 8)
    tile[i][tx] = src[(size_t)(s0 + i) * EMB + d0 + tx];
  __syncthreads();
#pragma unroll
  for (int i = ty; i < 32; i += 8)
    dst[(size_t)(d0 + i) * SEQ + s0 + tx] = tile[tx][i];
}

// ---- GEMM: A[M,K]bf16 x Bt[N,K]bf16 + bias(f32) (+gelu / +res f32) -------
__device__ __forceinline__ float gelu_f(float v) {
  float inner = 0.7978845608028654f * (v + 0.044715f * v * v * v);
  return 0.5f * v * (1.f + tanhf(inner));
}

template <int EPI, typename OT>  // bit0: +res, bit1: gelu
__global__ __launch_bounds__(256) void gemm_bt(
    const u16* __restrict__ A, const u16* __restrict__ Bt,
    const float* __restrict__ bias, const float* __restrict__ res,
    OT* __restrict__ C, int N, int K) {
  __shared__ u16 As[128 * 32];
  __shared__ u16 Bs[128 * 32];
  int nb = N >> 7;
  int mb = blockIdx.x / nb, nbi = blockIdx.x % nb;
  int m0 = mb << 7, n0 = nbi << 7;
  int t = threadIdx.x, l = t & 63, lg = l >> 4, lc = l & 15;
  int w = t >> 6;
  int wr = w >> 1, wc = w & 1;
  f32x4 acc[4][4] = {};
  int sr = t >> 2, sc = (t & 3) * 8;
  const u16* Ag = A + (size_t)(m0 + sr) * K + sc;
  const u16* Bg = Bt + (size_t)(n0 + sr) * K + sc;
  char* AsB = (char*)As + w * 1024;
  char* BsB = (char*)Bs + w * 1024;
  for (int k0 = 0; k0 < K; k0 += 32) {
    __syncthreads();  // previous iteration's LDS reads complete
    gload16(Ag + k0, AsB);
    gload16(Ag + k0 + (size_t)64 * K, AsB + 4096);
    gload16(Bg + k0, BsB);
    gload16(Bg + k0 + (size_t)64 * K, BsB + 4096);
    __syncthreads();  // staging complete (barrier drains vmcnt)
    bf16x8 af[4], bfv[4];
#pragma unroll
    for (int i = 0; i < 4; ++i)
      af[i] = *(const bf16x8*)(As + (wr * 64 + i * 16 + lc) * 32 + lg * 8);
#pragma unroll
    for (int j = 0; j < 4; ++j)
      bfv[j] = *(const bf16x8*)(Bs + (wc * 64 + j * 16 + lc) * 32 + lg * 8);
#pragma unroll
    for (int i = 0; i < 4; ++i)
#pragma unroll
      for (int j = 0; j < 4; ++j)
        acc[i][j] = __builtin_amdgcn_mfma_f32_16x16x32_bf16(af[i], bfv[j], acc[i][j], 0, 0, 0);
  }
#pragma unroll
  for (int i = 0; i < 4; ++i)
#pragma unroll
    for (int j = 0; j < 4; ++j) {
      int col = n0 + wc * 64 + j * 16 + lc;
      float bcol = bias[col];
#pragma unroll
      for (int r = 0; r < 4; ++r) {
        int row = m0 + wr * 64 + i * 16 + lg * 4 + r;
        float v = acc[i][j][r] + bcol;
        if (EPI & 2) v = gelu_f(v);
        if (EPI & 1) v += res[(size_t)row * N + col];
        if (sizeof(OT) == 2)
          C[(size_t)row * N + col] = (OT)f2bf(v);
        else
          C[(size_t)row * N + col] = (OT)v;
      }
    }
}

// ---- causal flash attention: independent waves, 16 q-rows each, KVB=64 ---
// K read direct from global (row-major), V read direct from pre-transposed
// VtG[bh][d][s] as contiguous 16B fragments. P bounced via per-wave swizzled
// LDS. No barriers. Longest-work-first wave order.
__global__ __launch_bounds__(256) void attn_kernel(
    const u16* __restrict__ Q, const u16* __restrict__ Kin,
    const u16* __restrict__ VtG, u16* __restrict__ O) {
  __shared__ u16 Ps[4][16 * 64];  // per-wave P tile, 128B rows
  int t = threadIdx.x, w = t >> 6, l = t & 63, lg = l >> 4, lc = l & 15;
  int nq = SEQ / 16;  // 128
  int wid = blockIdx.x * 4 + w;
  int qi = wid % nq, bh = wid / nq;
  int h = bh % HEADS, b = bh / HEADS;
  int wq0 = (nq - 1 - qi) * 16;  // longest first
  const u16* Qp = Q + (size_t)b * SEQ * EMB + h * HDIM;
  const u16* Kp = Kin + (size_t)b * SEQ * EMB + h * HDIM;
  const u16* Vt = VtG + (size_t)bh * HDIM * SEQ;
  u16* Op = O + (size_t)b * SEQ * EMB + h * HDIM;
  char* PsB = (char*)&Ps[w][0];

  // Q fragment with 1/8 scale folded in (exact: pow2 exponent shift)
  bf16x8 q0r = *(const bf16x8*)(Qp + (size_t)(wq0 + lc) * EMB + lg * 8);
  bf16x8 q1r = *(const bf16x8*)(Qp + (size_t)(wq0 + lc) * EMB + 32 + lg * 8);
  bf16x8 aq0, aq1;
#pragma unroll
  for (int j = 0; j < 8; ++j) {
    aq0[j] = (short)f2bf(bf2f((u16)q0r[j]) * 0.125f);
    aq1[j] = (short)f2bf(bf2f((u16)q1r[j]) * 0.125f);
  }

  f32x4 acc[4] = {};
  float mrow[4], lrow[4];
#pragma unroll
  for (int r = 0; r < 4; ++r) { mrow[r] = -1e30f; lrow[r] = 0.f; }

  int ntiles = (wq0 + 16 + 63) / 64;
  for (int ti = 0; ti < ntiles; ++ti) {
    int kv0 = ti * 64;
    // ---- QK^T: 4 column groups of 16 keys ----
    f32x4 sg[4];
#pragma unroll
    for (int g = 0; g < 4; ++g) {
      const u16* kr = Kp + (size_t)(kv0 + g * 16 + lc) * EMB;
      bf16x8 bk0 = *(const bf16x8*)(kr + lg * 8);
      bf16x8 bk1 = *(const bf16x8*)(kr + 32 + lg * 8);
      f32x4 z = {0.f, 0.f, 0.f, 0.f};
      z = __builtin_amdgcn_mfma_f32_16x16x32_bf16(aq0, bk0, z, 0, 0, 0);
      sg[g] = __builtin_amdgcn_mfma_f32_16x16x32_bf16(aq1, bk1, z, 0, 0, 0);
    }
    bool needmask = (kv0 + 63 > wq0);  // wave-uniform
    // ---- online softmax over 64 columns ----
#pragma unroll
    for (int r = 0; r < 4; ++r) {
      int prow = lg * 4 + r;
      float v[4];
#pragma unroll
      for (int g = 0; g < 4; ++g) {
        v[g] = sg[g][r];
        if (needmask && (kv0 + g * 16 + lc > wq0 + prow)) v[g] = -1e30f;
      }
      float tm = fmaxf(fmaxf(v[0], v[1]), fmaxf(v[2], v[3]));
#pragma unroll
      for (int mm = 1; mm < 16; mm <<= 1) tm = fmaxf(tm, __shfl_xor(tm, mm));
      float nm = fmaxf(mrow[r], tm);
      float e[4], ts = 0.f;
#pragma unroll
      for (int g = 0; g < 4; ++g) { e[g] = __expf(v[g] - nm); ts += e[g]; }
#pragma unroll
      for (int mm = 1; mm < 16; mm <<= 1) ts += __shfl_xor(ts, mm);
      float scl = __expf(mrow[r] - nm);
      lrow[r] = lrow[r] * scl + ts;
      mrow[r] = nm;
#pragma unroll
      for (int dc = 0; dc < 4; ++dc) acc[dc][r] *= scl;
#pragma unroll
      for (int g = 0; g < 4; ++g)
        *(u16*)(PsB + ((prow * 128 + (g * 16 + lc) * 2) ^ ((prow & 7) << 4))) =
            f2bf(e[g]);
    }
    // ---- PV: P[16x64] x V[64x64], V^T fragments from global ----
#pragma unroll
    for (int s = 0; s < 2; ++s) {
      int arow = lc;  // A-frag row = lane&15
      int po = (arow * 128 + s * 64 + lg * 16) ^ ((arow & 7) << 4);
      bf16x8 ap = *(const bf16x8*)(PsB + po);
#pragma unroll
      for (int dc = 0; dc < 4; ++dc) {
        bf16x8 bv = *(const bf16x8*)(Vt + (size_t)(dc * 16 + lc) * SEQ + kv0 +
                                     s * 32 + lg * 8);
        acc[dc] = __builtin_amdgcn_mfma_f32_16x16x32_bf16(ap, bv, acc[dc], 0, 0, 0);
      }
    }
  }
#pragma unroll
  for (int dc = 0; dc < 4; ++dc)
#pragma unroll
    for (int r = 0; r < 4; ++r) {
      int row = wq0 + lg * 4 + r;
      Op[(size_t)row * EMB + dc * 16 + lc] = f2bf(acc[dc][r] / lrow[r]);
    }
}

// ---- driver ---------------------------------------------------------------
extern "C" void kernel_launch(void* const* d_in, const int* in_sizes, int n_in,
                              void* d_out, int out_size, void* d_ws, size_t ws_size,
                              hipStream_t stream) {
  (void)in_sizes; (void)n_in; (void)out_size; (void)ws_size;
  const float* x   = (const float*)d_in[0];
  const float* Wq  = (const float*)d_in[1];
  const float* bq  = (const float*)d_in[2];
  const float* Wk  = (const float*)d_in[3];
  const float* bk  = (const float*)d_in[4];
  const float* Wv  = (const float*)d_in[5];
  const float* bv  = (const float*)d_in[6];
  const float* Wo  = (const float*)d_in[7];
  const float* bo  = (const float*)d_in[8];
  const float* W1  = (const float*)d_in[9];
  const float* b1  = (const float*)d_in[10];
  const float* W2  = (const float*)d_in[11];
  const float* b2  = (const float*)d_in[12];
  const float* g1  = (const float*)d_in[13];
  const float* be1 = (const float*)d_in[14];
  const float* g2  = (const float*)d_in[15];
  const float* be2 = (const float*)d_in[16];

  char* ws = (char*)d_ws;
  const size_t MB = 1ull << 20;
  u16*   WqT  = (u16*)(ws + 0 * MB);     // 2 MB
  u16*   WkT  = (u16*)(ws + 2 * MB);     // 2 MB
  u16*   WvT  = (u16*)(ws + 4 * MB);     // 2 MB
  u16*   WoT  = (u16*)(ws + 6 * MB);     // 2 MB
  u16*   W1T  = (u16*)(ws + 8 * MB);     // 8 MB
  u16*   W2T  = (u16*)(ws + 16 * MB);    // 8 MB
  u16*   hbuf = (u16*)(ws + 24 * MB);    // 16 MB: LN1 out, later ctx
  u16*   Kbuf = (u16*)(ws + 40 * MB);    // 16 MB: K, later h2
  float* x1f  = (float*)(ws + 56 * MB);  // 32 MB: attn residual out (f32)
  u16*   VtG  = (u16*)(ws + 56 * MB);    // 16 MB: V^T (dead before x1f written)
  u16*   Qbuf = (u16*)(ws + 88 * MB);    // 16 MB: Q (dead after attn)
  u16*   Vbuf = (u16*)(ws + 104 * MB);   // 16 MB: V (dead after attn)
  u16*   gbuf = (u16*)(ws + 88 * MB);    // 64 MB: FF1 out (overlaps dead Q,V)

  dim3 tb(32, 8);
  transpose_cvt<<<dim3(EMB / 32, EMB / 32), tb, 0, stream>>>(Wq, WqT, EMB, EMB);
  transpose_cvt<<<dim3(EMB / 32, EMB / 32), tb, 0, stream>>>(Wk, WkT, EMB, EMB);
  transpose_cvt<<<dim3(EMB / 32, EMB / 32), tb, 0, stream>>>(Wv, WvT, EMB, EMB);
  transpose_cvt<<<dim3(EMB / 32, EMB / 32), tb, 0, stream>>>(Wo, WoT, EMB, EMB);
  transpose_cvt<<<dim3(FFDIM / 32, EMB / 32), tb, 0, stream>>>(W1, W1T, EMB, FFDIM);
  transpose_cvt<<<dim3(EMB / 32, FFDIM / 32), tb, 0, stream>>>(W2, W2T, FFDIM, EMB);

  ln_kernel<<<MROWS / 4, 256, 0, stream>>>(x, g1, be1, hbuf);

  const int GQKV = (MROWS / 128) * (EMB / 128);    // 512
  const int GFF1 = (MROWS / 128) * (FFDIM / 128);  // 2048
  gemm_bt<0, u16><<<GQKV, 256, 0, stream>>>(hbuf, WqT, bq, nullptr, Qbuf, EMB, EMB);
  gemm_bt<0, u16><<<GQKV, 256, 0, stream>>>(hbuf, WkT, bk, nullptr, Kbuf, EMB, EMB);
  gemm_bt<0, u16><<<GQKV, 256, 0, stream>>>(hbuf, WvT, bv, nullptr, Vbuf, EMB, EMB);

  transpose_v<<<dim3(SEQ / 32, HDIM / 32, BSZ * HEADS), tb, 0, stream>>>(Vbuf, VtG);

  attn_kernel<<<BSZ * HEADS * (SEQ / 16) / 4, 256, 0, stream>>>(Qbuf, Kbuf, VtG, hbuf);

  gemm_bt<1, float><<<GQKV, 256, 0, stream>>>(hbuf, WoT, bo, x, x1f, EMB, EMB);

  ln_kernel<<<MROWS / 4, 256, 0, stream>>>(x1f, g2, be2, Kbuf);

  gemm_bt<2, u16><<<GFF1, 256, 0, stream>>>(Kbuf, W1T, b1, nullptr, gbuf, FFDIM, EMB);
  gemm_bt<1, float><<<GQKV, 256, 0, stream>>>(gbuf, W2T, b2, x1f, (float*)d_out, EMB, FFDIM);
}

// Round 6
// 509.536 us; speedup vs baseline: 1.6757x; 1.6757x over previous
//
#include <hip/hip_runtime.h>
#include <hip/hip_bf16.h>

#define EMB 1024
#define HEADS 16
#define HDIM 64
#define FFDIM 4096
#define BSZ 4
#define SEQ 2048
#define MROWS (BSZ * SEQ)
#define VSTRIDE 2080  // padded V^T row stride (breaks 4KB L2 camping)

typedef __attribute__((ext_vector_type(8))) short bf16x8;
typedef __attribute__((ext_vector_type(4))) float f32x4;
typedef __attribute__((ext_vector_type(16))) float f32x16;
typedef __attribute__((ext_vector_type(4))) unsigned short u16x4;
typedef unsigned short u16;

__device__ __forceinline__ float bf2f(u16 u) {
  union { unsigned int i; float f; } c; c.i = ((unsigned int)u) << 16; return c.f;
}
__device__ __forceinline__ u16 f2bf(float f) {
  union { float f; unsigned int i; } c; c.f = f;
  unsigned int i = c.i + 0x7fff + ((c.i >> 16) & 1);
  return (u16)(i >> 16);
}
__device__ __forceinline__ unsigned fbits(float f) {
  union { float f; unsigned u; } c; c.f = f; return c.u;
}
// truncating bf16 pair-pack: low16 = e0, high16 = e1 (P in [0,1], trunc ok)
__device__ __forceinline__ unsigned pk2(float e0, float e1) {
  return (fbits(e0) >> 16) | (fbits(e1) & 0xffff0000u);
}
__device__ __forceinline__ f32x16 zero16() {
  f32x16 z;
#pragma unroll
  for (int i = 0; i < 16; ++i) z[i] = 0.f;
  return z;
}
__device__ __forceinline__ void gload16(const u16* g, void* lds) {
  __builtin_amdgcn_global_load_lds(
      (const __attribute__((address_space(1))) void*)g,
      (__attribute__((address_space(3))) void*)lds, 16, 0, 0);
}

// ---- LayerNorm: f32 in -> bf16 out, one wave per row (4 rows/block) ------
__global__ __launch_bounds__(256) void ln_kernel(
    const float* __restrict__ x, const float* __restrict__ g,
    const float* __restrict__ be, u16* __restrict__ out) {
  int w = threadIdx.x >> 6, l = threadIdx.x & 63;
  size_t row = (size_t)blockIdx.x * 4 + w;
  const float* xr = x + row * EMB;
  float f[4][4];
  float s = 0.f, s2 = 0.f;
#pragma unroll
  for (int c = 0; c < 4; ++c) {
    f32x4 v = *(const f32x4*)(xr + c * 256 + l * 4);
#pragma unroll
    for (int j = 0; j < 4; ++j) {
      f[c][j] = v[j];
      s += v[j];
      s2 += v[j] * v[j];
    }
  }
#pragma unroll
  for (int m = 1; m < 64; m <<= 1) {
    s  += __shfl_xor(s, m);
    s2 += __shfl_xor(s2, m);
  }
  float mu = s * (1.f / EMB);
  float var = s2 * (1.f / EMB) - mu * mu;
  float rs = rsqrtf(var + 1e-5f);
#pragma unroll
  for (int c = 0; c < 4; ++c) {
    u16x4 o;
#pragma unroll
    for (int j = 0; j < 4; ++j) {
      int col = c * 256 + l * 4 + j;
      o[j] = f2bf((f[c][j] - mu) * rs * g[col] + be[col]);
    }
    *(u16x4*)(out + row * EMB + c * 256 + l * 4) = o;
  }
}

// ---- convert+transpose: f32 [R][C] -> bf16 [C][R] ------------------------
__global__ __launch_bounds__(256) void transpose_cvt(
    const float* __restrict__ in, u16* __restrict__ out, int R, int C) {
  __shared__ u16 tile[32][33];
  int c0 = blockIdx.x * 32, r0 = blockIdx.y * 32;
  int tx = threadIdx.x, ty = threadIdx.y;
#pragma unroll
  for (int i = ty; i < 32; i += 8)
    tile[i][tx] = f2bf(in[(size_t)(r0 + i) * C + c0 + tx]);
  __syncthreads();
#pragma unroll
  for (int i = ty; i < 32; i += 8)
    out[(size_t)(c0 + i) * R + r0 + tx] = tile[tx][i];
}

// ---- per-head V transpose: bf16 [b][s][h*64+d] -> Vt[bh][d][s] (padded) --
__global__ __launch_bounds__(256) void transpose_v(
    const u16* __restrict__ V, u16* __restrict__ Vt) {
  __shared__ u16 tile[32][33];
  int s0 = blockIdx.x * 32, d0 = blockIdx.y * 32, bh = blockIdx.z;
  int h = bh % HEADS, b = bh / HEADS;
  int tx = threadIdx.x, ty = threadIdx.y;
  const u16* src = V + (size_t)b * SEQ * EMB + h * HDIM;
  u16* dst = Vt + (size_t)bh * HDIM * VSTRIDE;
#pragma unroll
  for (int i = ty; i < 32; i += 8)
    tile[i][tx] = src[(size_t)(s0 + i) * EMB + d0 + tx];
  __syncthreads();
#pragma unroll
  for (int i = ty; i < 32; i += 8)
    dst[(size_t)(d0 + i) * VSTRIDE + s0 + tx] = tile[tx][i];
}

// ---- GEMM: A[M,K]bf16 x Bt[N,K]bf16 + bias(f32) (+gelu / +res f32) -------
__device__ __forceinline__ float gelu_f(float v) {
  float inner = 0.7978845608028654f * (v + 0.044715f * v * v * v);
  return 0.5f * v * (1.f + tanhf(inner));
}

template <int EPI, typename OT>  // bit0: +res, bit1: gelu
__global__ __launch_bounds__(256) void gemm_bt(
    const u16* __restrict__ A, const u16* __restrict__ Bt,
    const float* __restrict__ bias, const float* __restrict__ res,
    OT* __restrict__ C, int N, int K) {
  __shared__ u16 As[128 * 32];
  __shared__ u16 Bs[128 * 32];
  int nb = N >> 7;
  int mb = blockIdx.x / nb, nbi = blockIdx.x % nb;
  int m0 = mb << 7, n0 = nbi << 7;
  int t = threadIdx.x, l = t & 63, lg = l >> 4, lc = l & 15;
  int w = t >> 6;
  int wr = w >> 1, wc = w & 1;
  f32x4 acc[4][4] = {};
  int sr = t >> 2, sc = (t & 3) * 8;
  const u16* Ag = A + (size_t)(m0 + sr) * K + sc;
  const u16* Bg = Bt + (size_t)(n0 + sr) * K + sc;
  char* AsB = (char*)As + w * 1024;
  char* BsB = (char*)Bs + w * 1024;
  for (int k0 = 0; k0 < K; k0 += 32) {
    __syncthreads();
    gload16(Ag + k0, AsB);
    gload16(Ag + k0 + (size_t)64 * K, AsB + 4096);
    gload16(Bg + k0, BsB);
    gload16(Bg + k0 + (size_t)64 * K, BsB + 4096);
    __syncthreads();
    bf16x8 af[4], bfv[4];
#pragma unroll
    for (int i = 0; i < 4; ++i)
      af[i] = *(const bf16x8*)(As + (wr * 64 + i * 16 + lc) * 32 + lg * 8);
#pragma unroll
    for (int j = 0; j < 4; ++j)
      bfv[j] = *(const bf16x8*)(Bs + (wc * 64 + j * 16 + lc) * 32 + lg * 8);
#pragma unroll
    for (int i = 0; i < 4; ++i)
#pragma unroll
      for (int j = 0; j < 4; ++j)
        acc[i][j] = __builtin_amdgcn_mfma_f32_16x16x32_bf16(af[i], bfv[j], acc[i][j], 0, 0, 0);
  }
#pragma unroll
  for (int i = 0; i < 4; ++i)
#pragma unroll
    for (int j = 0; j < 4; ++j) {
      int col = n0 + wc * 64 + j * 16 + lc;
      float bcol = bias[col];
#pragma unroll
      for (int r = 0; r < 4; ++r) {
        int row = m0 + wr * 64 + i * 16 + lg * 4 + r;
        float v = acc[i][j][r] + bcol;
        if (EPI & 2) v = gelu_f(v);
        if (EPI & 1) v += res[(size_t)row * N + col];
        if (sizeof(OT) == 2)
          C[(size_t)row * N + col] = (OT)f2bf(v);
        else
          C[(size_t)row * N + col] = (OT)v;
      }
    }
}

// ---- causal flash attention: swapped QK^T, in-register softmax -----------
// Wave = q-tile pair (qi, 63-qi), 32 rows each => uniform 65 chunks/wave.
// S^T = mfma32x32x16(K, Q): lane owns one q-row (col = lane&31); row
// max/sum = 15 in-lane ops + 1 shfl_xor(32). P packed to bf16 in-register
// (trunc) + 1 shfl_xor(32) exchange per half -> PV B-frag. No LDS.
#define QKT32(ACCS, QF)                                                     \
  do {                                                                      \
    ACCS = zero16();                                                        \
    _Pragma("unroll") for (int s_ = 0; s_ < 4; ++s_)                        \
        ACCS = __builtin_amdgcn_mfma_f32_32x32x16_bf16(kf[s_], QF[s_],      \
                                                       ACCS, 0, 0, 0);      \
  } while (0)

#define ATTN_STEP(ACCS, M, L, O0, O1, DIAG)                                 \
  do {                                                                      \
    float e_[16];                                                           \
    float tm = -1e30f;                                                      \
    _Pragma("unroll") for (int i = 0; i < 16; ++i) {                        \
      float sv = ACCS[i];                                                   \
      if (DIAG) {                                                           \
        int kvl = (i & 3) + 8 * (i >> 2) + 4 * g;                           \
        if (kvl > lq) sv = -1e30f;                                          \
      }                                                                     \
      e_[i] = sv;                                                           \
      tm = fmaxf(tm, sv);                                                   \
    }                                                                       \
    tm = fmaxf(tm, __shfl_xor(tm, 32));                                     \
    float nm = fmaxf(M, tm);                                                \
    if (!__all(tm <= M)) {                                                  \
      float scl = __expf(M - nm);                                           \
      L *= scl;                                                             \
      _Pragma("unroll") for (int i = 0; i < 16; ++i) {                      \
        O0[i] *= scl;                                                       \
        O1[i] *= scl;                                                       \
      }                                                                     \
    }                                                                       \
    M = nm;                                                                 \
    float ts = 0.f;                                                         \
    _Pragma("unroll") for (int i = 0; i < 16; ++i) {                        \
      e_[i] = __expf(e_[i] - nm);                                           \
      ts += e_[i];                                                          \
    }                                                                       \
    ts += __shfl_xor(ts, 32);                                               \
    L += ts;                                                                \
    _Pragma("unroll") for (int s_ = 0; s_ < 2; ++s_) {                      \
      unsigned plo0 = pk2(e_[8 * s_ + 0], e_[8 * s_ + 1]);                  \
      unsigned plo1 = pk2(e_[8 * s_ + 2], e_[8 * s_ + 3]);                  \
      unsigned phi0 = pk2(e_[8 * s_ + 4], e_[8 * s_ + 5]);                  \
      unsigned phi1 = pk2(e_[8 * s_ + 6], e_[8 * s_ + 7]);                  \
      unsigned recv0 = __shfl_xor(g ? plo0 : phi0, 32);                     \
      unsigned recv1 = __shfl_xor(g ? plo1 : phi1, 32);                     \
      union { unsigned u[4]; bf16x8 v; } pf_;                               \
      pf_.u[0] = g ? recv0 : plo0;                                          \
      pf_.u[1] = g ? recv1 : plo1;                                          \
      pf_.u[2] = g ? phi0 : recv0;                                          \
      pf_.u[3] = g ? phi1 : recv1;                                          \
      O0 = __builtin_amdgcn_mfma_f32_32x32x16_bf16(vf[0][s_], pf_.v, O0,    \
                                                   0, 0, 0);                \
      O1 = __builtin_amdgcn_mfma_f32_32x32x16_bf16(vf[1][s_], pf_.v, O1,    \
                                                   0, 0, 0);                \
    }                                                                       \
  } while (0)

#define LOAD_KV(KV0)                                                        \
  do {                                                                      \
    _Pragma("unroll") for (int s_ = 0; s_ < 4; ++s_)                        \
        kf[s_] = *(const bf16x8*)(Kp + (size_t)((KV0) + lq) * EMB +         \
                                  s_ * 16 + g * 8);                         \
    _Pragma("unroll") for (int d_ = 0; d_ < 2; ++d_)                        \
        _Pragma("unroll") for (int s_ = 0; s_ < 2; ++s_)                    \
            vf[d_][s_] = *(const bf16x8*)(Vt +                              \
                (size_t)(d_ * 32 + lq) * VSTRIDE + (KV0) + s_ * 16 + g * 8);\
  } while (0)

#define WRITE_OUT(O0, O1, L, WQ0)                                           \
  do {                                                                      \
    float inv = 1.f / L;                                                    \
    u16* orow = Op + (size_t)((WQ0) + lq) * EMB;                            \
    _Pragma("unroll") for (int dblk = 0; dblk < 2; ++dblk) {                \
      _Pragma("unroll") for (int p = 0; p < 8; ++p) {                       \
        int i0 = 2 * p;                                                     \
        int d = dblk * 32 + 2 * (p & 1) + 8 * (p >> 1) + 4 * g;             \
        float v0 = (dblk ? O1[i0] : O0[i0]) * inv;                          \
        float v1 = (dblk ? O1[i0 + 1] : O0[i0 + 1]) * inv;                  \
        unsigned wd = (unsigned)f2bf(v0) | ((unsigned)f2bf(v1) << 16);      \
        *(unsigned*)(orow + d) = wd;                                        \
      }                                                                     \
    }                                                                       \
  } while (0)

__global__ __launch_bounds__(256, 2) void attn_kernel(
    const u16* __restrict__ Q, const u16* __restrict__ Kin,
    const u16* __restrict__ VtG, u16* __restrict__ O) {
  int t = threadIdx.x, w = t >> 6, l = t & 63;
  int lq = l & 31, g = l >> 5;
  int wid = blockIdx.x * 4 + w;
  int qi = wid & 31, bh = wid >> 5;
  int h = bh & (HEADS - 1), b = bh >> 4;
  int wq0a = qi * 32, wq0b = (63 - qi) * 32;
  int ntA = qi + 1, ntB = 64 - qi;
  const u16* Qp = Q + (size_t)b * SEQ * EMB + h * HDIM;
  const u16* Kp = Kin + (size_t)b * SEQ * EMB + h * HDIM;
  const u16* Vt = VtG + (size_t)bh * HDIM * VSTRIDE;
  u16* Op = O + (size_t)b * SEQ * EMB + h * HDIM;

  // Q fragments (B-operand), 1/8 prescale folded in (exact)
  bf16x8 qfA[4], qfB[4];
#pragma unroll
  for (int s = 0; s < 4; ++s) {
    bf16x8 ra = *(const bf16x8*)(Qp + (size_t)(wq0a + lq) * EMB + s * 16 + g * 8);
    bf16x8 rb = *(const bf16x8*)(Qp + (size_t)(wq0b + lq) * EMB + s * 16 + g * 8);
#pragma unroll
    for (int j = 0; j < 8; ++j) {
      qfA[s][j] = (short)f2bf(bf2f((u16)ra[j]) * 0.125f);
      qfB[s][j] = (short)f2bf(bf2f((u16)rb[j]) * 0.125f);
    }
  }

  f32x16 oA0 = zero16(), oA1 = zero16(), oB0 = zero16(), oB1 = zero16();
  f32x16 sA, sB;
  float mA = -1e30f, lA = 0.f, mB = -1e30f, lB = 0.f;
  bf16x8 kf[4], vf[2][2];

  for (int ti = 0; ti < ntA; ++ti) {
    int kv0 = ti * 32;
    LOAD_KV(kv0);
    QKT32(sA, qfA);
    QKT32(sB, qfB);
    bool diagA = (ti == ntA - 1);
    ATTN_STEP(sA, mA, lA, oA0, oA1, diagA);
    ATTN_STEP(sB, mB, lB, oB0, oB1, false);
  }
  WRITE_OUT(oA0, oA1, lA, wq0a);
  for (int ti = ntA; ti < ntB; ++ti) {
    int kv0 = ti * 32;
    LOAD_KV(kv0);
    QKT32(sB, qfB);
    bool diagB = (ti == ntB - 1);
    ATTN_STEP(sB, mB, lB, oB0, oB1, diagB);
  }
  WRITE_OUT(oB0, oB1, lB, wq0b);
}

// ---- driver ---------------------------------------------------------------
extern "C" void kernel_launch(void* const* d_in, const int* in_sizes, int n_in,
                              void* d_out, int out_size, void* d_ws, size_t ws_size,
                              hipStream_t stream) {
  (void)in_sizes; (void)n_in; (void)out_size; (void)ws_size;
  const float* x   = (const float*)d_in[0];
  const float* Wq  = (const float*)d_in[1];
  const float* bq  = (const float*)d_in[2];
  const float* Wk  = (const float*)d_in[3];
  const float* bk  = (const float*)d_in[4];
  const float* Wv  = (const float*)d_in[5];
  const float* bv  = (const float*)d_in[6];
  const float* Wo  = (const float*)d_in[7];
  const float* bo  = (const float*)d_in[8];
  const float* W1  = (const float*)d_in[9];
  const float* b1  = (const float*)d_in[10];
  const float* W2  = (const float*)d_in[11];
  const float* b2  = (const float*)d_in[12];
  const float* g1  = (const float*)d_in[13];
  const float* be1 = (const float*)d_in[14];
  const float* g2  = (const float*)d_in[15];
  const float* be2 = (const float*)d_in[16];

  char* ws = (char*)d_ws;
  const size_t MB = 1ull << 20;
  u16*   WqT  = (u16*)(ws + 0 * MB);     // 2 MB
  u16*   WkT  = (u16*)(ws + 2 * MB);     // 2 MB
  u16*   WvT  = (u16*)(ws + 4 * MB);     // 2 MB
  u16*   WoT  = (u16*)(ws + 6 * MB);     // 2 MB
  u16*   W1T  = (u16*)(ws + 8 * MB);     // 8 MB
  u16*   W2T  = (u16*)(ws + 16 * MB);    // 8 MB
  u16*   hbuf = (u16*)(ws + 24 * MB);    // 16 MB: LN1 out, later ctx
  u16*   Kbuf = (u16*)(ws + 40 * MB);    // 16 MB: K, later h2
  float* x1f  = (float*)(ws + 56 * MB);  // 32 MB: attn residual out (f32)
  u16*   VtG  = (u16*)(ws + 56 * MB);    // 17 MB: V^T (dead before x1f written)
  u16*   Qbuf = (u16*)(ws + 88 * MB);    // 16 MB: Q (dead after attn)
  u16*   Vbuf = (u16*)(ws + 104 * MB);   // 16 MB: V (dead after attn)
  u16*   gbuf = (u16*)(ws + 88 * MB);    // 64 MB: FF1 out (overlaps dead Q,V)

  dim3 tb(32, 8);
  transpose_cvt<<<dim3(EMB / 32, EMB / 32), tb, 0, stream>>>(Wq, WqT, EMB, EMB);
  transpose_cvt<<<dim3(EMB / 32, EMB / 32), tb, 0, stream>>>(Wk, WkT, EMB, EMB);
  transpose_cvt<<<dim3(EMB / 32, EMB / 32), tb, 0, stream>>>(Wv, WvT, EMB, EMB);
  transpose_cvt<<<dim3(EMB / 32, EMB / 32), tb, 0, stream>>>(Wo, WoT, EMB, EMB);
  transpose_cvt<<<dim3(FFDIM / 32, EMB / 32), tb, 0, stream>>>(W1, W1T, EMB, FFDIM);
  transpose_cvt<<<dim3(EMB / 32, FFDIM / 32), tb, 0, stream>>>(W2, W2T, FFDIM, EMB);

  ln_kernel<<<MROWS / 4, 256, 0, stream>>>(x, g1, be1, hbuf);

  const int GQKV = (MROWS / 128) * (EMB / 128);    // 512
  const int GFF1 = (MROWS / 128) * (FFDIM / 128);  // 2048
  gemm_bt<0, u16><<<GQKV, 256, 0, stream>>>(hbuf, WqT, bq, nullptr, Qbuf, EMB, EMB);
  gemm_bt<0, u16><<<GQKV, 256, 0, stream>>>(hbuf, WkT, bk, nullptr, Kbuf, EMB, EMB);
  gemm_bt<0, u16><<<GQKV, 256, 0, stream>>>(hbuf, WvT, bv, nullptr, Vbuf, EMB, EMB);

  transpose_v<<<dim3(SEQ / 32, HDIM / 32, BSZ * HEADS), tb, 0, stream>>>(Vbuf, VtG);

  // 2048 waves (pairs) / 4 per block = 512 blocks
  attn_kernel<<<BSZ * HEADS * (SEQ / 64) / 4, 256, 0, stream>>>(Qbuf, Kbuf, VtG, hbuf);

  gemm_bt<1, float><<<GQKV, 256, 0, stream>>>(hbuf, WoT, bo, x, x1f, EMB, EMB);

  ln_kernel<<<MROWS / 4, 256, 0, stream>>>(x1f, g2, be2, Kbuf);

  gemm_bt<2, u16><<<GFF1, 256, 0, stream>>>(Kbuf, W1T, b1, nullptr, gbuf, FFDIM, EMB);
  gemm_bt<1, float><<<GQKV, 256, 0, stream>>>(gbuf, W2T, b2, x1f, (float*)d_out, EMB, FFDIM);
}

// Round 7
// 448.006 us; speedup vs baseline: 1.9059x; 1.1373x over previous
//
#include <hip/hip_runtime.h>
#include <hip/hip_bf16.h>

#define EMB 1024
#define HEADS 16
#define HDIM 64
#define FFDIM 4096
#define BSZ 4
#define SEQ 2048
#define MROWS (BSZ * SEQ)
#define QKVW 3072
#define VSTRIDE 2080  // padded V^T row stride (breaks 4KB L2 camping)

typedef __attribute__((ext_vector_type(8))) short bf16x8;
typedef __attribute__((ext_vector_type(4))) float f32x4;
typedef __attribute__((ext_vector_type(16))) float f32x16;
typedef __attribute__((ext_vector_type(4))) unsigned short u16x4;
typedef unsigned short u16;

__device__ __forceinline__ float bf2f(u16 u) {
  union { unsigned int i; float f; } c; c.i = ((unsigned int)u) << 16; return c.f;
}
__device__ __forceinline__ u16 f2bf(float f) {
  union { float f; unsigned int i; } c; c.f = f;
  unsigned int i = c.i + 0x7fff + ((c.i >> 16) & 1);
  return (u16)(i >> 16);
}
__device__ __forceinline__ unsigned fbits(float f) {
  union { float f; unsigned u; } c; c.f = f; return c.u;
}
__device__ __forceinline__ unsigned pk2(float e0, float e1) {
  return (fbits(e0) >> 16) | (fbits(e1) & 0xffff0000u);
}
__device__ __forceinline__ f32x16 zero16() {
  f32x16 z;
#pragma unroll
  for (int i = 0; i < 16; ++i) z[i] = 0.f;
  return z;
}
__device__ __forceinline__ void gload16(const u16* g, void* lds) {
  __builtin_amdgcn_global_load_lds(
      (const __attribute__((address_space(1))) void*)g,
      (__attribute__((address_space(3))) void*)lds, 16, 0, 0);
}

// ---- LayerNorm: f32 in -> bf16 out, one wave per row (4 rows/block) ------
__global__ __launch_bounds__(256) void ln_kernel(
    const float* __restrict__ x, const float* __restrict__ g,
    const float* __restrict__ be, u16* __restrict__ out) {
  int w = threadIdx.x >> 6, l = threadIdx.x & 63;
  size_t row = (size_t)blockIdx.x * 4 + w;
  const float* xr = x + row * EMB;
  float f[4][4];
  float s = 0.f, s2 = 0.f;
#pragma unroll
  for (int c = 0; c < 4; ++c) {
    f32x4 v = *(const f32x4*)(xr + c * 256 + l * 4);
#pragma unroll
    for (int j = 0; j < 4; ++j) {
      f[c][j] = v[j];
      s += v[j];
      s2 += v[j] * v[j];
    }
  }
#pragma unroll
  for (int m = 1; m < 64; m <<= 1) {
    s  += __shfl_xor(s, m);
    s2 += __shfl_xor(s2, m);
  }
  float mu = s * (1.f / EMB);
  float var = s2 * (1.f / EMB) - mu * mu;
  float rs = rsqrtf(var + 1e-5f);
#pragma unroll
  for (int c = 0; c < 4; ++c) {
    u16x4 o;
#pragma unroll
    for (int j = 0; j < 4; ++j) {
      int col = c * 256 + l * 4 + j;
      o[j] = f2bf((f[c][j] - mu) * rs * g[col] + be[col]);
    }
    *(u16x4*)(out + row * EMB + c * 256 + l * 4) = o;
  }
}

// ---- convert+transpose: f32 [R][C] -> bf16 [C][R] ------------------------
__global__ __launch_bounds__(256) void transpose_cvt(
    const float* __restrict__ in, u16* __restrict__ out, int R, int C) {
  __shared__ u16 tile[32][33];
  int c0 = blockIdx.x * 32, r0 = blockIdx.y * 32;
  int tx = threadIdx.x, ty = threadIdx.y;
#pragma unroll
  for (int i = ty; i < 32; i += 8)
    tile[i][tx] = f2bf(in[(size_t)(r0 + i) * C + c0 + tx]);
  __syncthreads();
#pragma unroll
  for (int i = ty; i < 32; i += 8)
    out[(size_t)(c0 + i) * R + r0 + tx] = tile[tx][i];
}

// ---- concat QKV bias to f32[3072] ----------------------------------------
__global__ __launch_bounds__(256) void concat_bias(
    const float* __restrict__ a, const float* __restrict__ b,
    const float* __restrict__ c, float* __restrict__ o) {
  int i = blockIdx.x * 256 + threadIdx.x;
  o[i] = i < 1024 ? a[i] : (i < 2048 ? b[i - 1024] : c[i - 2048]);
}

// ---- per-head V transpose from fused qkv: -> Vt[bh][d][s] (padded) -------
__global__ __launch_bounds__(256) void transpose_v(
    const u16* __restrict__ QKV, u16* __restrict__ Vt) {
  __shared__ u16 tile[32][33];
  int s0 = blockIdx.x * 32, d0 = blockIdx.y * 32, bh = blockIdx.z;
  int h = bh % HEADS, b = bh / HEADS;
  int tx = threadIdx.x, ty = threadIdx.y;
  const u16* src = QKV + (size_t)b * SEQ * QKVW + 2048 + h * HDIM;
  u16* dst = Vt + (size_t)bh * HDIM * VSTRIDE;
#pragma unroll
  for (int i = ty; i < 32; i += 8)
    tile[i][tx] = src[(size_t)(s0 + i) * QKVW + d0 + tx];
  __syncthreads();
#pragma unroll
  for (int i = ty; i < 32; i += 8)
    dst[(size_t)(d0 + i) * VSTRIDE + s0 + tx] = tile[tx][i];
}

__device__ __forceinline__ float gelu_f(float v) {
  float inner = 0.7978845608028654f * (v + 0.044715f * v * v * v);
  return 0.5f * v * (1.f + tanhf(inner));
}

// ---- gemm8: 256x128 tile, 8 waves, BK=64, 3-buf LDS, counted vmcnt -------
// A[M,K] bf16, Bt[N,K] bf16 (pre-transposed), bias f32, optional res f32.
// LDS tile buf = 48KB: rows 0-255 A (128B swizzle-linear rows), 256-383 B.
// Swizzle: LDS(row, slot16B) holds global (row, slot ^ (row&7)).
template <int EPI, typename OT>  // EPI bit0: +res, bit1: gelu
__global__ __launch_bounds__(512, 1) void gemm8(
    const u16* __restrict__ A, const u16* __restrict__ Bt,
    const float* __restrict__ bias, const float* __restrict__ res,
    OT* __restrict__ C, int N, int K) {
  __shared__ u16 lds[3 * 24576];
  int nbn = N >> 7;
  int cpx = gridDim.x >> 3;
  int bid = blockIdx.x;
  int logical = (bid & 7) * cpx + (bid >> 3);  // XCD-contiguous
  int mb = logical / nbn, nb = logical % nbn;
  int m0 = mb << 8, n0 = nb << 7;
  int t = threadIdx.x, w = t >> 6, l = t & 63;
  int lg = l >> 4, lc = l & 15;
  int wr = w >> 2, wc = w & 3;
  int NT = K >> 6;
  int rsub = (w << 3) + (l >> 3);
  int slot_st = (l & 7) ^ (l >> 3);

  f32x4 acc[8][2] = {};

  // prologue: stage tiles 0, 1
#pragma unroll
  for (int tt = 0; tt < 2; ++tt) {
    u16* dst = lds + tt * 24576 + (w << 9);
#pragma unroll
    for (int s = 0; s < 6; ++s) {
      int row = (s << 6) + rsub;
      const u16* g = (s < 4)
          ? A + (size_t)(m0 + row) * K + (tt << 6) + (slot_st << 3)
          : Bt + (size_t)(n0 + row - 256) * K + (tt << 6) + (slot_st << 3);
      gload16(g, dst + (s << 12));
    }
  }
  asm volatile("s_waitcnt vmcnt(6)" ::: "memory");
  __builtin_amdgcn_s_barrier();

  for (int kt = 0; kt < NT; ++kt) {
    const u16* lb = lds + (kt % 3) * 24576;
    bool dost = (kt + 2) < NT;
    u16* sb = lds + ((kt + 2) % 3) * 24576 + (w << 9);
    int k2 = (kt + 2) << 6;

    // ---------- phase 0: m-frags 0..3 ----------
    if (dost) {
#pragma unroll
      for (int s = 0; s < 3; ++s) {
        int row = (s << 6) + rsub;
        gload16(A + (size_t)(m0 + row) * K + k2 + (slot_st << 3), sb + (s << 12));
      }
    }
    bf16x8 bfr[2][2];
#pragma unroll
    for (int j = 0; j < 2; ++j)
#pragma unroll
      for (int kk = 0; kk < 2; ++kk) {
        int row = 256 + (wc << 5) + (j << 4) + lc;
        int slot = ((kk << 2) + lg) ^ (lc & 7);
        bfr[j][kk] = *(const bf16x8*)(lb + row * 64 + (slot << 3));
      }
    bf16x8 afr[4][2];
#pragma unroll
    for (int i = 0; i < 4; ++i)
#pragma unroll
      for (int kk = 0; kk < 2; ++kk) {
        int row = (wr << 7) + (i << 4) + lc;
        int slot = ((kk << 2) + lg) ^ (lc & 7);
        afr[i][kk] = *(const bf16x8*)(lb + row * 64 + (slot << 3));
      }
    __builtin_amdgcn_s_barrier();
    __builtin_amdgcn_s_setprio(1);
#pragma unroll
    for (int i = 0; i < 4; ++i)
#pragma unroll
      for (int j = 0; j < 2; ++j)
#pragma unroll
        for (int kk = 0; kk < 2; ++kk)
          acc[i][j] = __builtin_amdgcn_mfma_f32_16x16x32_bf16(
              afr[i][kk], bfr[j][kk], acc[i][j], 0, 0, 0);
    __builtin_amdgcn_s_setprio(0);
    __builtin_amdgcn_s_barrier();

    // ---------- phase 1: m-frags 4..7 ----------
    if (dost) {
#pragma unroll
      for (int s = 3; s < 6; ++s) {
        int row = (s << 6) + rsub;
        const u16* g = (s < 4)
            ? A + (size_t)(m0 + row) * K + k2 + (slot_st << 3)
            : Bt + (size_t)(n0 + row - 256) * K + k2 + (slot_st << 3);
        gload16(g, sb + (s << 12));
      }
    }
    bf16x8 afr2[4][2];
#pragma unroll
    for (int i = 0; i < 4; ++i)
#pragma unroll
      for (int kk = 0; kk < 2; ++kk) {
        int row = (wr << 7) + ((i + 4) << 4) + lc;
        int slot = ((kk << 2) + lg) ^ (lc & 7);
        afr2[i][kk] = *(const bf16x8*)(lb + row * 64 + (slot << 3));
      }
    __builtin_amdgcn_s_barrier();
    __builtin_amdgcn_s_setprio(1);
#pragma unroll
    for (int i = 0; i < 4; ++i)
#pragma unroll
      for (int j = 0; j < 2; ++j)
#pragma unroll
        for (int kk = 0; kk < 2; ++kk)
          acc[i + 4][j] = __builtin_amdgcn_mfma_f32_16x16x32_bf16(
              afr2[i][kk], bfr[j][kk], acc[i + 4][j], 0, 0, 0);
    __builtin_amdgcn_s_setprio(0);
    if (dost)
      asm volatile("s_waitcnt vmcnt(6)" ::: "memory");
    else
      asm volatile("s_waitcnt vmcnt(0)" ::: "memory");
    __builtin_amdgcn_s_barrier();
  }

  // epilogue
#pragma unroll
  for (int i = 0; i < 8; ++i)
#pragma unroll
    for (int j = 0; j < 2; ++j) {
      int col = n0 + (wc << 5) + (j << 4) + lc;
      float bcol = bias[col];
#pragma unroll
      for (int r = 0; r < 4; ++r) {
        int row = m0 + (wr << 7) + (i << 4) + (lg << 2) + r;
        float v = acc[i][j][r] + bcol;
        if (EPI & 2) v = gelu_f(v);
        if (EPI & 1) v += res[(size_t)row * N + col];
        if (sizeof(OT) == 2)
          C[(size_t)row * N + col] = (OT)f2bf(v);
        else
          C[(size_t)row * N + col] = (OT)v;
      }
    }
}

// ---- causal flash attention: swapped QK^T, in-register softmax -----------
#define QKT32(ACCS, QF)                                                     \
  do {                                                                      \
    ACCS = zero16();                                                        \
    _Pragma("unroll") for (int s_ = 0; s_ < 4; ++s_)                        \
        ACCS = __builtin_amdgcn_mfma_f32_32x32x16_bf16(kf[s_], QF[s_],      \
                                                       ACCS, 0, 0, 0);      \
  } while (0)

#define ATTN_STEP(ACCS, M, L, O0, O1, DIAG)                                 \
  do {                                                                      \
    float e_[16];                                                           \
    float tm = -1e30f;                                                      \
    _Pragma("unroll") for (int i = 0; i < 16; ++i) {                        \
      float sv = ACCS[i];                                                   \
      if (DIAG) {                                                           \
        int kvl = (i & 3) + 8 * (i >> 2) + 4 * g;                           \
        if (kvl > lq) sv = -1e30f;                                          \
      }                                                                     \
      e_[i] = sv;                                                           \
      tm = fmaxf(tm, sv);                                                   \
    }                                                                       \
    tm = fmaxf(tm, __shfl_xor(tm, 32));                                     \
    float nm = fmaxf(M, tm);                                                \
    if (!__all(tm <= M)) {                                                  \
      float scl = __expf(M - nm);                                           \
      L *= scl;                                                             \
      _Pragma("unroll") for (int i = 0; i < 16; ++i) {                      \
        O0[i] *= scl;                                                       \
        O1[i] *= scl;                                                       \
      }                                                                     \
    }                                                                       \
    M = nm;                                                                 \
    float ts = 0.f;                                                         \
    _Pragma("unroll") for (int i = 0; i < 16; ++i) {                        \
      e_[i] = __expf(e_[i] - nm);                                           \
      ts += e_[i];                                                          \
    }                                                                       \
    ts += __shfl_xor(ts, 32);                                               \
    L += ts;                                                                \
    _Pragma("unroll") for (int s_ = 0; s_ < 2; ++s_) {                      \
      unsigned plo0 = pk2(e_[8 * s_ + 0], e_[8 * s_ + 1]);                  \
      unsigned plo1 = pk2(e_[8 * s_ + 2], e_[8 * s_ + 3]);                  \
      unsigned phi0 = pk2(e_[8 * s_ + 4], e_[8 * s_ + 5]);                  \
      unsigned phi1 = pk2(e_[8 * s_ + 6], e_[8 * s_ + 7]);                  \
      unsigned recv0 = __shfl_xor(g ? plo0 : phi0, 32);                     \
      unsigned recv1 = __shfl_xor(g ? plo1 : phi1, 32);                     \
      union { unsigned u[4]; bf16x8 v; } pf_;                               \
      pf_.u[0] = g ? recv0 : plo0;                                          \
      pf_.u[1] = g ? recv1 : plo1;                                          \
      pf_.u[2] = g ? phi0 : recv0;                                          \
      pf_.u[3] = g ? phi1 : recv1;                                          \
      O0 = __builtin_amdgcn_mfma_f32_32x32x16_bf16(vf[0][s_], pf_.v, O0,    \
                                                   0, 0, 0);                \
      O1 = __builtin_amdgcn_mfma_f32_32x32x16_bf16(vf[1][s_], pf_.v, O1,    \
                                                   0, 0, 0);                \
    }                                                                       \
  } while (0)

#define LOAD_KV(KV0)                                                        \
  do {                                                                      \
    _Pragma("unroll") for (int s_ = 0; s_ < 4; ++s_)                        \
        kf[s_] = *(const bf16x8*)(Kp + (size_t)((KV0) + lq) * QKVW +        \
                                  s_ * 16 + g * 8);                         \
    _Pragma("unroll") for (int d_ = 0; d_ < 2; ++d_)                        \
        _Pragma("unroll") for (int s_ = 0; s_ < 2; ++s_)                    \
            vf[d_][s_] = *(const bf16x8*)(Vt +                              \
                (size_t)(d_ * 32 + lq) * VSTRIDE + (KV0) + s_ * 16 + g * 8);\
  } while (0)

#define WRITE_OUT(O0, O1, L, WQ0)                                           \
  do {                                                                      \
    float inv = 1.f / L;                                                    \
    u16* orow = Op + (size_t)((WQ0) + lq) * EMB;                            \
    _Pragma("unroll") for (int dblk = 0; dblk < 2; ++dblk) {                \
      _Pragma("unroll") for (int p = 0; p < 8; ++p) {                       \
        int i0 = 2 * p;                                                     \
        int d = dblk * 32 + 2 * (p & 1) + 8 * (p >> 1) + 4 * g;             \
        float v0 = (dblk ? O1[i0] : O0[i0]) * inv;                          \
        float v1 = (dblk ? O1[i0 + 1] : O0[i0 + 1]) * inv;                  \
        unsigned wd = (unsigned)f2bf(v0) | ((unsigned)f2bf(v1) << 16);      \
        *(unsigned*)(orow + d) = wd;                                        \
      }                                                                     \
    }                                                                       \
  } while (0)

__global__ __launch_bounds__(256, 2) void attn_kernel(
    const u16* __restrict__ QKV, const u16* __restrict__ VtG,
    u16* __restrict__ O) {
  int t = threadIdx.x, w = t >> 6, l = t & 63;
  int lq = l & 31, g = l >> 5;
  int wid = blockIdx.x * 4 + w;
  int qi = wid & 31, bh = wid >> 5;
  int h = bh & (HEADS - 1), b = bh >> 4;
  int wq0a = qi * 32, wq0b = (63 - qi) * 32;
  int ntA = qi + 1, ntB = 64 - qi;
  const u16* Qp = QKV + (size_t)b * SEQ * QKVW + h * HDIM;
  const u16* Kp = QKV + (size_t)b * SEQ * QKVW + 1024 + h * HDIM;
  const u16* Vt = VtG + (size_t)bh * HDIM * VSTRIDE;
  u16* Op = O + (size_t)b * SEQ * EMB + h * HDIM;

  bf16x8 qfA[4], qfB[4];
#pragma unroll
  for (int s = 0; s < 4; ++s) {
    bf16x8 ra = *(const bf16x8*)(Qp + (size_t)(wq0a + lq) * QKVW + s * 16 + g * 8);
    bf16x8 rb = *(const bf16x8*)(Qp + (size_t)(wq0b + lq) * QKVW + s * 16 + g * 8);
#pragma unroll
    for (int j = 0; j < 8; ++j) {
      qfA[s][j] = (short)f2bf(bf2f((u16)ra[j]) * 0.125f);
      qfB[s][j] = (short)f2bf(bf2f((u16)rb[j]) * 0.125f);
    }
  }

  f32x16 oA0 = zero16(), oA1 = zero16(), oB0 = zero16(), oB1 = zero16();
  f32x16 sA, sB;
  float mA = -1e30f, lA = 0.f, mB = -1e30f, lB = 0.f;
  bf16x8 kf[4], vf[2][2];

  for (int ti = 0; ti < ntA; ++ti) {
    int kv0 = ti * 32;
    LOAD_KV(kv0);
    QKT32(sA, qfA);
    QKT32(sB, qfB);
    bool diagA = (ti == ntA - 1);
    ATTN_STEP(sA, mA, lA, oA0, oA1, diagA);
    ATTN_STEP(sB, mB, lB, oB0, oB1, false);
  }
  WRITE_OUT(oA0, oA1, lA, wq0a);
  for (int ti = ntA; ti < ntB; ++ti) {
    int kv0 = ti * 32;
    LOAD_KV(kv0);
    QKT32(sB, qfB);
    bool diagB = (ti == ntB - 1);
    ATTN_STEP(sB, mB, lB, oB0, oB1, diagB);
  }
  WRITE_OUT(oB0, oB1, lB, wq0b);
}

// ---- driver ---------------------------------------------------------------
extern "C" void kernel_launch(void* const* d_in, const int* in_sizes, int n_in,
                              void* d_out, int out_size, void* d_ws, size_t ws_size,
                              hipStream_t stream) {
  (void)in_sizes; (void)n_in; (void)out_size; (void)ws_size;
  const float* x   = (const float*)d_in[0];
  const float* Wq  = (const float*)d_in[1];
  const float* bq  = (const float*)d_in[2];
  const float* Wk  = (const float*)d_in[3];
  const float* bk  = (const float*)d_in[4];
  const float* Wv  = (const float*)d_in[5];
  const float* bv  = (const float*)d_in[6];
  const float* Wo  = (const float*)d_in[7];
  const float* bo  = (const float*)d_in[8];
  const float* W1  = (const float*)d_in[9];
  const float* b1  = (const float*)d_in[10];
  const float* W2  = (const float*)d_in[11];
  const float* b2  = (const float*)d_in[12];
  const float* g1  = (const float*)d_in[13];
  const float* be1 = (const float*)d_in[14];
  const float* g2  = (const float*)d_in[15];
  const float* be2 = (const float*)d_in[16];

  char* ws = (char*)d_ws;
  const size_t MB = 1ull << 20;
  u16*   WqkvT = (u16*)(ws + 0 * MB);    // 6 MB: [3072][1024]
  u16*   WoT   = (u16*)(ws + 6 * MB);    // 2 MB
  u16*   W1T   = (u16*)(ws + 8 * MB);    // 8 MB
  u16*   W2T   = (u16*)(ws + 16 * MB);   // 8 MB
  float* bqkv  = (float*)(ws + 24 * MB); // 12 KB
  u16*   hbuf  = (u16*)(ws + 25 * MB);   // 16 MB: LN1 out -> ctx -> h2
  float* x1f   = (float*)(ws + 41 * MB); // 32 MB
  u16*   qkv   = (u16*)(ws + 73 * MB);   // 48 MB: fused QKV [M][3072]
  u16*   VtG   = (u16*)(ws + 121 * MB);  // 16.3 MB
  u16*   gbuf  = (u16*)(ws + 73 * MB);   // 64 MB: FF1 out (overlays dead qkv+VtG)

  dim3 tb(32, 8);
  transpose_cvt<<<dim3(EMB / 32, EMB / 32), tb, 0, stream>>>(Wq, WqkvT, EMB, EMB);
  transpose_cvt<<<dim3(EMB / 32, EMB / 32), tb, 0, stream>>>(Wk, WqkvT + 1024 * 1024, EMB, EMB);
  transpose_cvt<<<dim3(EMB / 32, EMB / 32), tb, 0, stream>>>(Wv, WqkvT + 2 * 1024 * 1024, EMB, EMB);
  transpose_cvt<<<dim3(EMB / 32, EMB / 32), tb, 0, stream>>>(Wo, WoT, EMB, EMB);
  transpose_cvt<<<dim3(FFDIM / 32, EMB / 32), tb, 0, stream>>>(W1, W1T, EMB, FFDIM);
  transpose_cvt<<<dim3(EMB / 32, FFDIM / 32), tb, 0, stream>>>(W2, W2T, FFDIM, EMB);
  concat_bias<<<12, 256, 0, stream>>>(bq, bk, bv, bqkv);

  ln_kernel<<<MROWS / 4, 256, 0, stream>>>(x, g1, be1, hbuf);

  // fused QKV: [8192,1024] x [3072,1024]^T -> [8192,3072]
  gemm8<0, u16><<<(MROWS / 256) * (QKVW / 128), 512, 0, stream>>>(
      hbuf, WqkvT, bqkv, nullptr, qkv, QKVW, EMB);

  transpose_v<<<dim3(SEQ / 32, HDIM / 32, BSZ * HEADS), tb, 0, stream>>>(qkv, VtG);

  attn_kernel<<<BSZ * HEADS * (SEQ / 64) / 4, 256, 0, stream>>>(qkv, VtG, hbuf);

  gemm8<1, float><<<(MROWS / 256) * (EMB / 128), 512, 0, stream>>>(
      hbuf, WoT, bo, x, x1f, EMB, EMB);

  ln_kernel<<<MROWS / 4, 256, 0, stream>>>(x1f, g2, be2, hbuf);

  gemm8<2, u16><<<(MROWS / 256) * (FFDIM / 128), 512, 0, stream>>>(
      hbuf, W1T, b1, nullptr, gbuf, FFDIM, EMB);
  gemm8<1, float><<<(MROWS / 256) * (EMB / 128), 512, 0, stream>>>(
      gbuf, W2T, b2, x1f, (float*)d_out, EMB, FFDIM);
}